// Round 1
// 316.224 us; speedup vs baseline: 1.1792x; 1.1792x over previous
//
#include <hip/hip_runtime.h>
#include <math.h>

#define B_   8192
#define D_   2048
#define C_   1000
#define L_   256
#define BIN_CAP 64
#define ORTH_BLOCKS 2048

typedef unsigned short bf16raw;

__device__ __forceinline__ float bflo(unsigned int u) { return __uint_as_float(u << 16); }
__device__ __forceinline__ float bfhi(unsigned int u) { return __uint_as_float(u & 0xffff0000u); }

// round-to-nearest-even f32 -> bf16 bits (finite inputs)
__device__ __forceinline__ bf16raw f2b(float f) {
  unsigned int x = __float_as_uint(f);
  unsigned int r = (x + 0x7fffu + ((x >> 16) & 1u)) >> 16;
  return (bf16raw)r;
}

__device__ __forceinline__ void dec8(uint4 u, float* x) {
  x[0] = bflo(u.x); x[1] = bfhi(u.x);
  x[2] = bflo(u.y); x[3] = bfhi(u.y);
  x[4] = bflo(u.z); x[5] = bfhi(u.z);
  x[6] = bflo(u.w); x[7] = bfhi(u.w);
}

__device__ __forceinline__ float waveSum(float v) {
#pragma unroll
  for (int off = 32; off > 0; off >>= 1) v += __shfl_xor(v, off, 64);
  return v;
}

__device__ __forceinline__ float blockSum(float v, float* lds4) {
  v = waveSum(v);
  const int wave = threadIdx.x >> 6;
  if ((threadIdx.x & 63) == 0) lds4[wave] = v;
  __syncthreads();
  v = lds4[0] + lds4[1] + lds4[2] + lds4[3];
  __syncthreads();
  return v;
}

// load 8 consecutive-per-thread elements of a row (rowbase in ELEMENTS), runtime mode
__device__ __forceinline__ void load8rt(const void* p, size_t rowbase, int t, int isb,
                                        float* x) {
  if (isb) {
    const uint4 v = ((const uint4*)((const bf16raw*)p + rowbase))[t];
    dec8(v, x);
  } else {
    const float4* q = (const float4*)((const float*)p + rowbase);
    const float4 v0 = q[2 * t], v1 = q[2 * t + 1];
    x[0] = v0.x; x[1] = v0.y; x[2] = v0.z; x[3] = v0.w;
    x[4] = v1.x; x[5] = v1.y; x[6] = v1.z; x[7] = v1.w;
  }
}

// ---- detect: is float data packed bf16 (1) or f32 (0)? ------------------
__global__ __launch_bounds__(256) void detect_kernel(const unsigned int* feat_words,
                                                     int* flag) {
  __shared__ float lds4[4];
  const unsigned int w = feat_words[threadIdx.x];
  const float v = bflo(w);  // low 16 bits as bf16
  const float a = fabsf(v);
  float hit = (a > 1e-3f && a < 10.f) ? 1.f : 0.f;
  hit = blockSum(hit, lds4);
  if (threadIdx.x == 0) *flag = (hit > 128.f) ? 1 : 0;
}

// ---- init: zero scratch --------------------------------------------------
__global__ __launch_bounds__(256) void init_kernel(int* counts, float* accs,
                                                   float* p_final) {
  const int t = blockIdx.x * 256 + threadIdx.x;
  if (t < 2 * L_) counts[t] = 0;
  if (t < 16) accs[t] = 0.f;
  if (t < 2 * C_) p_final[t] = 0.f;
}

// ---- MSEL phase A: bin rows by (modal, label) ---------------------------
__global__ __launch_bounds__(256) void bin_kernel(const int* labels, const int* modal,
                                                  int* counts, int* rowlist) {
  const int r = blockIdx.x * 256 + threadIdx.x;
  if (r >= B_) return;
  const int m = modal[r] ? 1 : 0;
  int lb = labels[r]; lb = lb < 0 ? 0 : (lb >= L_ ? L_ - 1 : lb);
  const int key = m * L_ + lb;
  const int idx = atomicAdd(&counts[key], 1);
  if (idx < BIN_CAP) rowlist[key * BIN_CAP + idx] = r;
}

// ---- fused wave-per-row: orth dots (blocks < ORTH_BLOCKS) + feat inv-norms ----
// One 64-lane wave owns one full row (32 elems/lane). No __syncthreads in the
// reduction path; all vector loads issued before any arithmetic.
__global__ __launch_bounds__(256) void rowdot_kernel(const void* f1, const void* f2,
                                                     const void* f3, const void* feat,
                                                     float* orth_part, float* norms,
                                                     const int* flag) {
  __shared__ float lsum[4][3];
  const int t = threadIdx.x;
  const int wave = t >> 6, lane = t & 63;
  const int isb = *flag;

  if (blockIdx.x < ORTH_BLOCKS) {
    const int row = blockIdx.x * 4 + wave;
    const size_t base = (size_t)row * D_;
    float v[6] = {0.f, 0.f, 0.f, 0.f, 0.f, 0.f};
    if (isb) {
      const uint4* qa = (const uint4*)((const bf16raw*)f1 + base);
      const uint4* qb = (const uint4*)((const bf16raw*)f2 + base);
      const uint4* qc = (const uint4*)((const bf16raw*)f3 + base);
      uint4 A[4], Bv[4], Cv[4];
#pragma unroll
      for (int j = 0; j < 4; ++j) A[j] = qa[j * 64 + lane];
#pragma unroll
      for (int j = 0; j < 4; ++j) Bv[j] = qb[j * 64 + lane];
#pragma unroll
      for (int j = 0; j < 4; ++j) Cv[j] = qc[j * 64 + lane];
#pragma unroll
      for (int j = 0; j < 4; ++j) {
        float a[8], b[8], c[8];
        dec8(A[j], a); dec8(Bv[j], b); dec8(Cv[j], c);
#pragma unroll
        for (int k = 0; k < 8; ++k) {
          v[0] += a[k] * a[k]; v[1] += b[k] * b[k]; v[2] += c[k] * c[k];
          v[3] += a[k] * b[k]; v[4] += a[k] * c[k]; v[5] += b[k] * c[k];
        }
      }
    } else {
      const float4* qa = (const float4*)((const float*)f1 + base);
      const float4* qb = (const float4*)((const float*)f2 + base);
      const float4* qc = (const float4*)((const float*)f3 + base);
#pragma unroll
      for (int h = 0; h < 2; ++h) {
        float4 A[4], Bv[4], Cv[4];
#pragma unroll
        for (int j = 0; j < 4; ++j) A[j] = qa[(h * 4 + j) * 64 + lane];
#pragma unroll
        for (int j = 0; j < 4; ++j) Bv[j] = qb[(h * 4 + j) * 64 + lane];
#pragma unroll
        for (int j = 0; j < 4; ++j) Cv[j] = qc[(h * 4 + j) * 64 + lane];
#pragma unroll
        for (int j = 0; j < 4; ++j) {
          const float a[4] = {A[j].x, A[j].y, A[j].z, A[j].w};
          const float b[4] = {Bv[j].x, Bv[j].y, Bv[j].z, Bv[j].w};
          const float c[4] = {Cv[j].x, Cv[j].y, Cv[j].z, Cv[j].w};
#pragma unroll
          for (int k = 0; k < 4; ++k) {
            v[0] += a[k] * a[k]; v[1] += b[k] * b[k]; v[2] += c[k] * c[k];
            v[3] += a[k] * b[k]; v[4] += a[k] * c[k]; v[5] += b[k] * c[k];
          }
        }
      }
    }
    // interleaved 6-chain butterfly: full sums land in every lane
#pragma unroll
    for (int off = 32; off > 0; off >>= 1) {
#pragma unroll
      for (int j = 0; j < 6; ++j) v[j] += __shfl_xor(v[j], off, 64);
    }
    const float q1 = fmaxf(sqrtf(v[0]), 1e-12f);
    const float q2 = fmaxf(sqrtf(v[1]), 1e-12f);
    const float q3 = fmaxf(sqrtf(v[2]), 1e-12f);
    if (lane == 0) {
      lsum[wave][0] = fabsf(v[3]) / (q1 * q2);
      lsum[wave][1] = fabsf(v[4]) / (q1 * q3);
      lsum[wave][2] = fabsf(v[5]) / (q2 * q3);
    }
    __syncthreads();
    if (t < 3) {
      orth_part[t * ORTH_BLOCKS + blockIdx.x] =
          lsum[0][t] + lsum[1][t] + lsum[2][t] + lsum[3][t];
    }
  } else {
    // feat inverse row norms for MSEL
    const int row = (blockIdx.x - ORTH_BLOCKS) * 4 + wave;
    const size_t base = (size_t)row * D_;
    float ss = 0.f;
    if (isb) {
      const uint4* q = (const uint4*)((const bf16raw*)feat + base);
      uint4 X[4];
#pragma unroll
      for (int j = 0; j < 4; ++j) X[j] = q[j * 64 + lane];
#pragma unroll
      for (int j = 0; j < 4; ++j) {
        float x[8]; dec8(X[j], x);
#pragma unroll
        for (int k = 0; k < 8; ++k) ss += x[k] * x[k];
      }
    } else {
      const float4* q = (const float4*)((const float*)feat + base);
#pragma unroll
      for (int j = 0; j < 8; ++j) {
        const float4 w = q[j * 64 + lane];
        ss += w.x * w.x + w.y * w.y + w.z * w.z + w.w * w.w;
      }
    }
    ss = waveSum(ss);
    if (lane == 0) norms[row] = 1.f / fmaxf(sqrtf(ss), 1e-12f);
  }
}

// ---- Consistency: softmax + per-modal sums (2-row pipelined) -------------
__device__ __forceinline__ void loadlogits(const void* logits, int r, int lane, int isb,
                                           float* x) {
#pragma unroll
  for (int kk = 0; kk < 4; ++kk) {
    const int idx = lane + (kk << 6);  // 4-element group index, valid < 250
    if (idx < (C_ / 4)) {
      if (isb) {
        const uint2 w = ((const uint2*)((const bf16raw*)logits + (size_t)r * C_))[idx];
        x[4 * kk + 0] = bflo(w.x); x[4 * kk + 1] = bfhi(w.x);
        x[4 * kk + 2] = bflo(w.y); x[4 * kk + 3] = bfhi(w.y);
      } else {
        const float4 w = ((const float4*)((const float*)logits + (size_t)r * C_))[idx];
        x[4 * kk + 0] = w.x; x[4 * kk + 1] = w.y;
        x[4 * kk + 2] = w.z; x[4 * kk + 3] = w.w;
      }
    } else {
      x[4 * kk + 0] = -INFINITY; x[4 * kk + 1] = -INFINITY;
      x[4 * kk + 2] = -INFINITY; x[4 * kk + 3] = -INFINITY;
    }
  }
}

__global__ __launch_bounds__(256) void cons_kernel(const void* logits, const int* modal,
                                                   float* p_final, const int* flag) {
  __shared__ float wacc[4][2][1024];  // 32 KB
  const int t = threadIdx.x;
  const int wave = t >> 6, lane = t & 63;
  const int isb = *flag;
  float accA[16], accB[16];
#pragma unroll
  for (int k = 0; k < 16; ++k) { accA[k] = 0.f; accB[k] = 0.f; }
  const int rbase = blockIdx.x * 32 + wave * 8;
#pragma unroll
  for (int i = 0; i < 8; i += 2) {
    const int r0 = rbase + i, r1 = rbase + i + 1;
    float x[16], y[16];
    loadlogits(logits, r0, lane, isb, x);
    loadlogits(logits, r1, lane, isb, y);
    float mx = -INFINITY, my = -INFINITY;
#pragma unroll
    for (int k = 0; k < 16; ++k) { mx = fmaxf(mx, x[k]); my = fmaxf(my, y[k]); }
#pragma unroll
    for (int off = 32; off > 0; off >>= 1) {
      mx = fmaxf(mx, __shfl_xor(mx, off, 64));
      my = fmaxf(my, __shfl_xor(my, off, 64));
    }
    float sx = 0.f, sy = 0.f;
#pragma unroll
    for (int k = 0; k < 16; ++k) {
      x[k] = expf(x[k] - mx); sx += x[k];
      y[k] = expf(y[k] - my); sy += y[k];
    }
#pragma unroll
    for (int off = 32; off > 0; off >>= 1) {
      sx += __shfl_xor(sx, off, 64);
      sy += __shfl_xor(sy, off, 64);
    }
    const float ivx = 1.f / sx, ivy = 1.f / sy;
    if (modal[r0] == 0) {
#pragma unroll
      for (int k = 0; k < 16; ++k) accA[k] += x[k] * ivx;
    } else {
#pragma unroll
      for (int k = 0; k < 16; ++k) accB[k] += x[k] * ivx;
    }
    if (modal[r1] == 0) {
#pragma unroll
      for (int k = 0; k < 16; ++k) accA[k] += y[k] * ivy;
    } else {
#pragma unroll
      for (int k = 0; k < 16; ++k) accB[k] += y[k] * ivy;
    }
  }
#pragma unroll
  for (int k = 0; k < 16; ++k) {
    const int c = 4 * (lane + ((k >> 2) << 6)) + (k & 3);  // < 1024: pad region ok
    wacc[wave][0][c] = accA[k];
    wacc[wave][1][c] = accB[k];
  }
  __syncthreads();
  for (int e = t; e < 2 * C_; e += 256) {
    const int m = (e < C_) ? 0 : 1;
    const int c = e - m * C_;
    atomicAdd(&p_final[e], wacc[0][m][c] + wacc[1][m][c] + wacc[2][m][c] + wacc[3][m][c]);
  }
}

// ---- MSEL fused center+label: one block per label, precomputed norms -----
__global__ __launch_bounds__(256) void label_kernel(const void* feat, const int* counts,
                                                    const int* rowlist, const float* norms,
                                                    float* accs, const int* flag) {
  __shared__ float lds4[4];
  const int l = blockIdx.x;
  const int t = threadIdx.x;
  const int isb = *flag;
  const int nr_true = counts[l];
  const int ns_true = counts[L_ + l];
  const int nr = nr_true < BIN_CAP ? nr_true : BIN_CAP;
  const int ns = ns_true < BIN_CAP ? ns_true : BIN_CAP;
  const int tot = nr + ns;
  float accR[8], accS[8];
#pragma unroll
  for (int j = 0; j < 8; ++j) { accR[j] = 0.f; accS[j] = 0.f; }
  for (int i = 0; i < tot; i += 2) {
    const int i1 = i + 1;
    const int key0 = (i < nr) ? l : (L_ + l);
    const int idx0 = (i < nr) ? i : (i - nr);
    const int r0 = rowlist[key0 * BIN_CAP + idx0];
    const bool have1 = (i1 < tot);
    const int key1 = (i1 < nr) ? l : (L_ + l);
    const int idx1 = (i1 < nr) ? i1 : (i1 - nr);
    const int r1 = have1 ? rowlist[key1 * BIN_CAP + idx1] : r0;
    const float rn0 = norms[r0];
    const float rn1 = have1 ? norms[r1] : 0.f;
    float x0[8], x1[8];
    load8rt(feat, (size_t)r0 * D_, t, isb, x0);
    load8rt(feat, (size_t)r1 * D_, t, isb, x1);
    if (i < nr) {
#pragma unroll
      for (int j = 0; j < 8; ++j) accR[j] += x0[j] * rn0;
    } else {
#pragma unroll
      for (int j = 0; j < 8; ++j) accS[j] += x0[j] * rn0;
    }
    if (i1 < nr) {
#pragma unroll
      for (int j = 0; j < 8; ++j) accR[j] += x1[j] * rn1;
    } else {
#pragma unroll
      for (int j = 0; j < 8; ++j) accS[j] += x1[j] * rn1;
    }
  }
  float rr = 0.f, rs = 0.f;
#pragma unroll
  for (int j = 0; j < 8; ++j) { rr += accR[j] * accR[j]; rs += accR[j] * accS[j]; }
  rr = blockSum(rr, lds4);
  rs = blockSum(rs, lds4);
  if (t == 0 && nr_true >= 2 && ns_true >= 1) {
    const float fr = (float)nr_true, fs = (float)ns_true;
    const float diff = rr / (fr * fr) - rs / (fr * fs);  // c_rr - c_rs
    atomicAdd(&accs[3], diff * diff);
    atomicAdd(&accs[4], 1.0f);
  }
}

// ---- Final combine: reduce orth partials, KL, MSEL; store f32/bf16 -------
__global__ __launch_bounds__(256) void InnovationLoss_88124138979690_kernel(
    const float* p_final, const int* counts, const float* accs, const float* orth_part,
    void* out, const int* flag) {
  __shared__ float lds4[4];
  const int t = threadIdx.x;
  const float nr = blockSum((float)counts[t], lds4);        // total rgb rows
  const float ns = blockSum((float)counts[L_ + t], lds4);   // total sar rows
  const float fr = fmaxf(nr, 1.f), fs = fmaxf(ns, 1.f);
  float klp = 0.f;
  for (int c = t; c < C_; c += 256) {
    const float pr = p_final[c] / fr;
    const float ps = p_final[C_ + c] / fs;
    klp += (ps - pr) * (logf(ps) - logf(pr));
  }
  klp = blockSum(klp, lds4);
  float o0 = 0.f, o1 = 0.f, o2 = 0.f;
  for (int b = t; b < ORTH_BLOCKS; b += 256) {
    o0 += orth_part[b];
    o1 += orth_part[ORTH_BLOCKS + b];
    o2 += orth_part[2 * ORTH_BLOCKS + b];
  }
  o0 = blockSum(o0, lds4);
  o1 = blockSum(o1, lds4);
  o2 = blockSum(o2, lds4);
  if (t == 0) {
    const float kl = (nr > 0.f && ns > 0.f) ? 0.5f * klp : 0.f;
    const float msel_cnt = accs[4];
    const float msel = msel_cnt > 0.f ? accs[3] / fmaxf(msel_cnt, 1.f) : 0.f;
    const float orth = (o0 + o1 + o2) * (1.0f / (float)B_);
    const float res = 0.5f * msel + 0.1f * orth + 0.1f * kl;
    if (*flag) ((bf16raw*)out)[0] = f2b(res);   // bf16 output (2 bytes)
    else       ((float*)out)[0]   = res;        // f32 output (4 bytes)
  }
}

extern "C" __attribute__((visibility("default")))
void kernel_launch(void* const* d_in, const int* in_sizes, int n_in,
                   void* d_out, int out_size, void* d_ws, size_t ws_size,
                   hipStream_t stream) {
  const void* feat   = d_in[0];
  const void* dee1   = d_in[1];
  const void* dee2   = d_in[2];
  const void* dee3   = d_in[3];
  const void* logits = d_in[4];
  const int*  labels = (const int*)d_in[5];
  const int*  modal  = (const int*)d_in[6];

  // workspace layout (198,592 bytes total):
  //   counts    @ 0      : 512 i32      (2,048 B)
  //   accs      @ 2048   : 16 f32       (64 B)  [3]=msel_sum [4]=msel_cnt
  //   p_final   @ 2112   : 2000 f32     (8,000 B)
  //   rowlist   @ 10112  : 512*64 i32   (131,072 B)
  //   flag      @ 141184 : 1 i32
  //   norms     @ 141248 : 8192 f32     (32,768 B)
  //   orth_part @ 174016 : 3*2048 f32   (24,576 B)
  char* ws = (char*)d_ws;
  int*   counts    = (int*)  (ws);
  float* accs      = (float*)(ws + 2048);
  float* p_final   = (float*)(ws + 2112);
  int*   rowlist   = (int*)  (ws + 10112);
  int*   flag      = (int*)  (ws + 141184);
  float* norms     = (float*)(ws + 141248);
  float* orth_part = (float*)(ws + 174016);

  detect_kernel<<<1, 256, 0, stream>>>((const unsigned int*)feat, flag);
  init_kernel<<<8, 256, 0, stream>>>(counts, accs, p_final);
  bin_kernel<<<B_ / 256, 256, 0, stream>>>(labels, modal, counts, rowlist);
  rowdot_kernel<<<2 * ORTH_BLOCKS, 256, 0, stream>>>(dee1, dee2, dee3, feat, orth_part,
                                                     norms, flag);
  cons_kernel<<<B_ / 32, 256, 0, stream>>>(logits, modal, p_final, flag);
  label_kernel<<<L_, 256, 0, stream>>>(feat, counts, rowlist, norms, accs, flag);
  InnovationLoss_88124138979690_kernel<<<1, 256, 0, stream>>>(p_final, counts, accs,
                                                              orth_part, d_out, flag);
}

// Round 2
// 310.949 us; speedup vs baseline: 1.1992x; 1.0170x over previous
//
#include <hip/hip_runtime.h>
#include <math.h>

#define B_   8192
#define D_   2048
#define C_   1000
#define L_   256
#define BIN_CAP 64

#define ORTH_BLK  256   // 4 waves/blk * 8 rows/wave  -> 8192 rows
#define NORM_BLK  128   // 4 waves/blk * 16 rows/wave -> 8192 rows
#define CONS_BLK  512   // 16 rows/blk (4 rows/wave)  -> 8192 rows
#define FUSED_GRID (ORTH_BLK + NORM_BLK + CONS_BLK)
#define ORTH_WAVES (ORTH_BLK * 4)   // 1024 partial-sum slots

typedef unsigned short bf16raw;

__device__ __forceinline__ float bflo(unsigned int u) { return __uint_as_float(u << 16); }
__device__ __forceinline__ float bfhi(unsigned int u) { return __uint_as_float(u & 0xffff0000u); }

// round-to-nearest-even f32 -> bf16 bits (finite inputs)
__device__ __forceinline__ bf16raw f2b(float f) {
  unsigned int x = __float_as_uint(f);
  unsigned int r = (x + 0x7fffu + ((x >> 16) & 1u)) >> 16;
  return (bf16raw)r;
}

__device__ __forceinline__ void dec8(uint4 u, float* x) {
  x[0] = bflo(u.x); x[1] = bfhi(u.x);
  x[2] = bflo(u.y); x[3] = bfhi(u.y);
  x[4] = bflo(u.z); x[5] = bfhi(u.z);
  x[6] = bflo(u.w); x[7] = bfhi(u.w);
}

__device__ __forceinline__ float waveSum(float v) {
#pragma unroll
  for (int off = 32; off > 0; off >>= 1) v += __shfl_xor(v, off, 64);
  return v;
}

__device__ __forceinline__ float blockSum(float v, float* lds4) {
  v = waveSum(v);
  const int wave = threadIdx.x >> 6;
  if ((threadIdx.x & 63) == 0) lds4[wave] = v;
  __syncthreads();
  v = lds4[0] + lds4[1] + lds4[2] + lds4[3];
  __syncthreads();
  return v;
}

// ---- detect: is float data packed bf16 (1) or f32 (0)? ------------------
__global__ __launch_bounds__(256) void detect_kernel(const unsigned int* feat_words,
                                                     int* flag) {
  __shared__ float lds4[4];
  const unsigned int w = feat_words[threadIdx.x];
  const float v = bflo(w);  // low 16 bits as bf16
  const float a = fabsf(v);
  float hit = (a > 1e-3f && a < 10.f) ? 1.f : 0.f;
  hit = blockSum(hit, lds4);
  if (threadIdx.x == 0) *flag = (hit > 128.f) ? 1 : 0;
}

// ---- init: zero scratch --------------------------------------------------
__global__ __launch_bounds__(256) void init_kernel(int* counts, float* accs,
                                                   float* p_final) {
  const int t = blockIdx.x * 256 + threadIdx.x;
  if (t < 2 * L_) counts[t] = 0;
  if (t < 16) accs[t] = 0.f;
  if (t < 2 * C_) p_final[t] = 0.f;
}

// ---- MSEL phase A: bin rows by (modal, label) ---------------------------
__global__ __launch_bounds__(256) void bin_kernel(const int* labels, const int* modal,
                                                  int* counts, int* rowlist) {
  const int r = blockIdx.x * 256 + threadIdx.x;
  if (r >= B_) return;
  const int m = modal[r] ? 1 : 0;
  int lb = labels[r]; lb = lb < 0 ? 0 : (lb >= L_ ? L_ - 1 : lb);
  const int key = m * L_ + lb;
  const int idx = atomicAdd(&counts[key], 1);
  if (idx < BIN_CAP) rowlist[key * BIN_CAP + idx] = r;
}

// ---- helpers for the fused streaming kernel ------------------------------
__device__ __forceinline__ void ldrow3(const bf16raw* pa, const bf16raw* pb,
                                       const bf16raw* pc, size_t base, int lane,
                                       uint4 (&A)[4], uint4 (&Bv)[4], uint4 (&Cv)[4]) {
  const uint4* qa = (const uint4*)(pa + base);
  const uint4* qb = (const uint4*)(pb + base);
  const uint4* qc = (const uint4*)(pc + base);
#pragma unroll
  for (int j = 0; j < 4; ++j) A[j] = qa[j * 64 + lane];
#pragma unroll
  for (int j = 0; j < 4; ++j) Bv[j] = qb[j * 64 + lane];
#pragma unroll
  for (int j = 0; j < 4; ++j) Cv[j] = qc[j * 64 + lane];
}

__device__ __forceinline__ void orth_rowacc(const uint4 (&A)[4], const uint4 (&Bv)[4],
                                            const uint4 (&Cv)[4], float (&v)[6]) {
#pragma unroll
  for (int j = 0; j < 4; ++j) {
    float a[8], b[8], c[8];
    dec8(A[j], a); dec8(Bv[j], b); dec8(Cv[j], c);
#pragma unroll
    for (int k = 0; k < 8; ++k) {
      v[0] += a[k] * a[k]; v[1] += b[k] * b[k]; v[2] += c[k] * c[k];
      v[3] += a[k] * b[k]; v[4] += a[k] * c[k]; v[5] += b[k] * c[k];
    }
  }
}

__device__ __forceinline__ float ssq4(const uint4 (&X)[4]) {
  float ss = 0.f;
#pragma unroll
  for (int j = 0; j < 4; ++j) {
    float x[8]; dec8(X[j], x);
#pragma unroll
    for (int k = 0; k < 8; ++k) ss += x[k] * x[k];
  }
  return ss;
}

__device__ __forceinline__ void loadlogits_f32(const void* logits, int r, int lane,
                                               float (&x)[16]) {
#pragma unroll
  for (int kk = 0; kk < 4; ++kk) {
    const int idx = lane + (kk << 6);  // valid < 250
    if (idx < (C_ / 4)) {
      const float4 w = ((const float4*)((const float*)logits + (size_t)r * C_))[idx];
      x[4 * kk + 0] = w.x; x[4 * kk + 1] = w.y;
      x[4 * kk + 2] = w.z; x[4 * kk + 3] = w.w;
    } else {
      x[4 * kk + 0] = -INFINITY; x[4 * kk + 1] = -INFINITY;
      x[4 * kk + 2] = -INFINITY; x[4 * kk + 3] = -INFINITY;
    }
  }
}

__device__ __forceinline__ void softmax_acc(float (&x)[16], int m, float (&accA)[16],
                                            float (&accB)[16]) {
  float mx = -INFINITY;
#pragma unroll
  for (int k = 0; k < 16; ++k) mx = fmaxf(mx, x[k]);
#pragma unroll
  for (int off = 32; off > 0; off >>= 1) mx = fmaxf(mx, __shfl_xor(mx, off, 64));
  float s = 0.f;
#pragma unroll
  for (int k = 0; k < 16; ++k) { x[k] = expf(x[k] - mx); s += x[k]; }
#pragma unroll
  for (int off = 32; off > 0; off >>= 1) s += __shfl_xor(s, off, 64);
  const float inv = 1.f / s;
  if (m == 0) {
#pragma unroll
    for (int k = 0; k < 16; ++k) accA[k] += x[k] * inv;
  } else {
#pragma unroll
    for (int k = 0; k < 16; ++k) accB[k] += x[k] * inv;
  }
}

// ---- fused streaming kernel: orth dots | feat norms | consistency -------
// 896 blocks (all resident): long-lived waves, register double-buffered so
// the memory pipe never starves.
__global__ __launch_bounds__(256) void fused_stream_kernel(
    const void* f1, const void* f2, const void* f3, const void* feat,
    const void* logits, const int* modal, float* orth_part, float* norms,
    float* p_final, const int* flag) {
  __shared__ float wacc[4][2][1024];  // used by cons blocks only (32 KB)
  const int t = threadIdx.x;
  const int wave = t >> 6, lane = t & 63;
  const int isb = *flag;
  const int bx = blockIdx.x;

  if (bx < ORTH_BLK) {
    // ---- orthogonality: 1 wave = 8 rows, register double-buffer ----
    const int gw = bx * 4 + wave;  // 0..1023
    float s12 = 0.f, s13 = 0.f, s23 = 0.f;
    if (isb) {
      const bf16raw* pa = (const bf16raw*)f1;
      const bf16raw* pb = (const bf16raw*)f2;
      const bf16raw* pc = (const bf16raw*)f3;
      const size_t base0 = (size_t)gw * (8 * D_);
      uint4 A0[4], B0[4], C0[4], A1[4], B1[4], C1[4];
      ldrow3(pa, pb, pc, base0, lane, A0, B0, C0);
#pragma unroll
      for (int r = 0; r < 8; ++r) {
        if (r < 7) {
          const size_t nb = base0 + (size_t)(r + 1) * D_;
          if (r & 1) ldrow3(pa, pb, pc, nb, lane, A0, B0, C0);
          else       ldrow3(pa, pb, pc, nb, lane, A1, B1, C1);
        }
        float v[6] = {0.f, 0.f, 0.f, 0.f, 0.f, 0.f};
        if (r & 1) orth_rowacc(A1, B1, C1, v);
        else       orth_rowacc(A0, B0, C0, v);
#pragma unroll
        for (int off = 32; off > 0; off >>= 1) {
#pragma unroll
          for (int j = 0; j < 6; ++j) v[j] += __shfl_xor(v[j], off, 64);
        }
        const float q1 = fmaxf(sqrtf(v[0]), 1e-12f);
        const float q2 = fmaxf(sqrtf(v[1]), 1e-12f);
        const float q3 = fmaxf(sqrtf(v[2]), 1e-12f);
        s12 += fabsf(v[3]) / (q1 * q2);
        s13 += fabsf(v[4]) / (q1 * q3);
        s23 += fabsf(v[5]) / (q2 * q3);
      }
    } else {
      for (int r = 0; r < 8; ++r) {
        const size_t base = ((size_t)gw * 8 + r) * D_;
        const float4* qa = (const float4*)((const float*)f1 + base);
        const float4* qb = (const float4*)((const float*)f2 + base);
        const float4* qc = (const float4*)((const float*)f3 + base);
        float v[6] = {0.f, 0.f, 0.f, 0.f, 0.f, 0.f};
#pragma unroll
        for (int h = 0; h < 8; ++h) {
          const float4 a4 = qa[h * 64 + lane];
          const float4 b4 = qb[h * 64 + lane];
          const float4 c4 = qc[h * 64 + lane];
          const float a[4] = {a4.x, a4.y, a4.z, a4.w};
          const float b[4] = {b4.x, b4.y, b4.z, b4.w};
          const float c[4] = {c4.x, c4.y, c4.z, c4.w};
#pragma unroll
          for (int k = 0; k < 4; ++k) {
            v[0] += a[k] * a[k]; v[1] += b[k] * b[k]; v[2] += c[k] * c[k];
            v[3] += a[k] * b[k]; v[4] += a[k] * c[k]; v[5] += b[k] * c[k];
          }
        }
#pragma unroll
        for (int off = 32; off > 0; off >>= 1) {
#pragma unroll
          for (int j = 0; j < 6; ++j) v[j] += __shfl_xor(v[j], off, 64);
        }
        const float q1 = fmaxf(sqrtf(v[0]), 1e-12f);
        const float q2 = fmaxf(sqrtf(v[1]), 1e-12f);
        const float q3 = fmaxf(sqrtf(v[2]), 1e-12f);
        s12 += fabsf(v[3]) / (q1 * q2);
        s13 += fabsf(v[4]) / (q1 * q3);
        s23 += fabsf(v[5]) / (q2 * q3);
      }
    }
    if (lane == 0) {
      orth_part[gw] = s12;
      orth_part[ORTH_WAVES + gw] = s13;
      orth_part[2 * ORTH_WAVES + gw] = s23;
    }
  } else if (bx < ORTH_BLK + NORM_BLK) {
    // ---- feat inverse row norms: 1 wave = 16 rows, double-buffered ----
    const int gw = (bx - ORTH_BLK) * 4 + wave;  // 0..511
    const size_t base0 = (size_t)gw * (16 * D_);
    if (isb) {
      const bf16raw* pf = (const bf16raw*)feat;
      uint4 X0[4], X1[4];
      {
        const uint4* q = (const uint4*)(pf + base0);
#pragma unroll
        for (int j = 0; j < 4; ++j) X0[j] = q[j * 64 + lane];
      }
#pragma unroll
      for (int r = 0; r < 16; ++r) {
        if (r < 15) {
          const uint4* q = (const uint4*)(pf + base0 + (size_t)(r + 1) * D_);
          if (r & 1) {
#pragma unroll
            for (int j = 0; j < 4; ++j) X0[j] = q[j * 64 + lane];
          } else {
#pragma unroll
            for (int j = 0; j < 4; ++j) X1[j] = q[j * 64 + lane];
          }
        }
        float ss = (r & 1) ? ssq4(X1) : ssq4(X0);
        ss = waveSum(ss);
        if (lane == 0) norms[gw * 16 + r] = 1.f / fmaxf(sqrtf(ss), 1e-12f);
      }
    } else {
      for (int r = 0; r < 16; ++r) {
        const float4* q = (const float4*)((const float*)feat + base0 + (size_t)r * D_);
        float ss = 0.f;
#pragma unroll
        for (int j = 0; j < 8; ++j) {
          const float4 w = q[j * 64 + lane];
          ss += w.x * w.x + w.y * w.y + w.z * w.z + w.w * w.w;
        }
        ss = waveSum(ss);
        if (lane == 0) norms[gw * 16 + r] = 1.f / fmaxf(sqrtf(ss), 1e-12f);
      }
    }
  } else {
    // ---- consistency: 1 wave = 4 rows, row-ahead prefetch ----
    const int cb = bx - ORTH_BLK - NORM_BLK;  // 0..511
    const int rbase = cb * 16 + wave * 4;
    float accA[16], accB[16];
#pragma unroll
    for (int k = 0; k < 16; ++k) { accA[k] = 0.f; accB[k] = 0.f; }
    if (isb) {
      const bf16raw* pl = (const bf16raw*)logits;
      uint4 W0a, W1a;
      uint4 W0b = make_uint4(0u, 0u, 0u, 0u), W1b = make_uint4(0u, 0u, 0u, 0u);
      int ma, mb = 0;
      {
        const uint4* q = (const uint4*)(pl + (size_t)rbase * C_);
        W0a = q[lane];
        W1a = (lane < 61) ? q[64 + lane] : make_uint4(0u, 0u, 0u, 0u);
        ma = modal[rbase];
      }
#pragma unroll
      for (int i = 0; i < 4; ++i) {
        if (i < 3) {
          const int rn = rbase + i + 1;
          const uint4* q = (const uint4*)(pl + (size_t)rn * C_);
          W0b = q[lane];
          W1b = (lane < 61) ? q[64 + lane] : make_uint4(0u, 0u, 0u, 0u);
          mb = modal[rn];
        }
        float x[16];
        dec8(W0a, x);
        if (lane < 61) {
          float xx[8]; dec8(W1a, xx);
#pragma unroll
          for (int k = 0; k < 8; ++k) x[8 + k] = xx[k];
        } else {
#pragma unroll
          for (int k = 0; k < 8; ++k) x[8 + k] = -INFINITY;
        }
        softmax_acc(x, ma, accA, accB);
        W0a = W0b; W1a = W1b; ma = mb;
      }
#pragma unroll
      for (int k = 0; k < 16; ++k) {
        const int c = (k < 8) ? (8 * lane + k) : (512 + 8 * lane + (k - 8));
        wacc[wave][0][c] = accA[k];
        wacc[wave][1][c] = accB[k];
      }
    } else {
      float xa[16], xb[16];
      int ma, mb = 0;
      loadlogits_f32(logits, rbase, lane, xa);
      ma = modal[rbase];
#pragma unroll
      for (int i = 0; i < 4; ++i) {
        if (i < 3) {
          loadlogits_f32(logits, rbase + i + 1, lane, xb);
          mb = modal[rbase + i + 1];
        }
        softmax_acc(xa, ma, accA, accB);
#pragma unroll
        for (int k = 0; k < 16; ++k) xa[k] = xb[k];
        ma = mb;
      }
#pragma unroll
      for (int k = 0; k < 16; ++k) {
        const int c = 4 * (lane + ((k >> 2) << 6)) + (k & 3);
        wacc[wave][0][c] = accA[k];
        wacc[wave][1][c] = accB[k];
      }
    }
    __syncthreads();
    for (int e = t; e < 2 * C_; e += 256) {
      const int m = (e < C_) ? 0 : 1;
      const int c = e - m * C_;
      atomicAdd(&p_final[e],
                wacc[0][m][c] + wacc[1][m][c] + wacc[2][m][c] + wacc[3][m][c]);
    }
  }
}

// ---- MSEL fused center+label: one block per label, 2-ahead prefetch ------
__global__ __launch_bounds__(256) void label_kernel(const void* feat, const int* counts,
                                                    const int* rowlist, const float* norms,
                                                    float* accs, const int* flag) {
  __shared__ float lds4[4];
  const int l = blockIdx.x;
  const int t = threadIdx.x;
  const int isb = *flag;
  const int nr_true = counts[l];
  const int ns_true = counts[L_ + l];
  const int nr = nr_true < BIN_CAP ? nr_true : BIN_CAP;
  const int ns = ns_true < BIN_CAP ? ns_true : BIN_CAP;
  const int tot = nr + ns;
  float accR[8], accS[8];
#pragma unroll
  for (int j = 0; j < 8; ++j) { accR[j] = 0.f; accS[j] = 0.f; }

  if (tot > 0) {
    auto rowAt = [&](int i) -> int {
      const int key = (i < nr) ? l : (L_ + l);
      const int idx = (i < nr) ? i : (i - nr);
      return rowlist[key * BIN_CAP + idx];
    };
    if (isb) {
      const bf16raw* pf = (const bf16raw*)feat;
      const int r0 = rowAt(0);
      uint4 qa = ((const uint4*)(pf + (size_t)r0 * D_))[t];
      float na = norms[r0];
      uint4 qb = make_uint4(0u, 0u, 0u, 0u);
      float nb2 = 0.f;
      if (tot > 1) {
        const int r1 = rowAt(1);
        qb = ((const uint4*)(pf + (size_t)r1 * D_))[t];
        nb2 = norms[r1];
      }
      for (int i = 0; i < tot; i += 2) {
        uint4 qc = make_uint4(0u, 0u, 0u, 0u), qd = make_uint4(0u, 0u, 0u, 0u);
        float nc = 0.f, nd = 0.f;
        if (i + 2 < tot) {
          const int rc = rowAt(i + 2);
          qc = ((const uint4*)(pf + (size_t)rc * D_))[t];
          nc = norms[rc];
        }
        if (i + 3 < tot) {
          const int rd = rowAt(i + 3);
          qd = ((const uint4*)(pf + (size_t)rd * D_))[t];
          nd = norms[rd];
        }
        {
          float x[8]; dec8(qa, x);
          if (i < nr) {
#pragma unroll
            for (int j = 0; j < 8; ++j) accR[j] += x[j] * na;
          } else {
#pragma unroll
            for (int j = 0; j < 8; ++j) accS[j] += x[j] * na;
          }
        }
        if (i + 1 < tot) {
          float x[8]; dec8(qb, x);
          if (i + 1 < nr) {
#pragma unroll
            for (int j = 0; j < 8; ++j) accR[j] += x[j] * nb2;
          } else {
#pragma unroll
            for (int j = 0; j < 8; ++j) accS[j] += x[j] * nb2;
          }
        }
        qa = qc; qb = qd; na = nc; nb2 = nd;
      }
    } else {
      const float* pf = (const float*)feat;
      const int r0 = rowAt(0);
      float4 a0 = ((const float4*)(pf + (size_t)r0 * D_))[2 * t];
      float4 a1 = ((const float4*)(pf + (size_t)r0 * D_))[2 * t + 1];
      float na = norms[r0];
      float4 b0 = make_float4(0.f, 0.f, 0.f, 0.f), b1 = make_float4(0.f, 0.f, 0.f, 0.f);
      float nb2 = 0.f;
      if (tot > 1) {
        const int r1 = rowAt(1);
        b0 = ((const float4*)(pf + (size_t)r1 * D_))[2 * t];
        b1 = ((const float4*)(pf + (size_t)r1 * D_))[2 * t + 1];
        nb2 = norms[r1];
      }
      for (int i = 0; i < tot; i += 2) {
        float4 c0 = make_float4(0.f, 0.f, 0.f, 0.f), c1 = c0, d0 = c0, d1 = c0;
        float nc = 0.f, nd = 0.f;
        if (i + 2 < tot) {
          const int rc = rowAt(i + 2);
          c0 = ((const float4*)(pf + (size_t)rc * D_))[2 * t];
          c1 = ((const float4*)(pf + (size_t)rc * D_))[2 * t + 1];
          nc = norms[rc];
        }
        if (i + 3 < tot) {
          const int rd = rowAt(i + 3);
          d0 = ((const float4*)(pf + (size_t)rd * D_))[2 * t];
          d1 = ((const float4*)(pf + (size_t)rd * D_))[2 * t + 1];
          nd = norms[rd];
        }
        {
          const float x[8] = {a0.x, a0.y, a0.z, a0.w, a1.x, a1.y, a1.z, a1.w};
          if (i < nr) {
#pragma unroll
            for (int j = 0; j < 8; ++j) accR[j] += x[j] * na;
          } else {
#pragma unroll
            for (int j = 0; j < 8; ++j) accS[j] += x[j] * na;
          }
        }
        if (i + 1 < tot) {
          const float x[8] = {b0.x, b0.y, b0.z, b0.w, b1.x, b1.y, b1.z, b1.w};
          if (i + 1 < nr) {
#pragma unroll
            for (int j = 0; j < 8; ++j) accR[j] += x[j] * nb2;
          } else {
#pragma unroll
            for (int j = 0; j < 8; ++j) accS[j] += x[j] * nb2;
          }
        }
        a0 = c0; a1 = c1; b0 = d0; b1 = d1; na = nc; nb2 = nd;
      }
    }
  }
  float rr = 0.f, rs = 0.f;
#pragma unroll
  for (int j = 0; j < 8; ++j) { rr += accR[j] * accR[j]; rs += accR[j] * accS[j]; }
  rr = blockSum(rr, lds4);
  rs = blockSum(rs, lds4);
  if (t == 0 && nr_true >= 2 && ns_true >= 1) {
    const float fr = (float)nr_true, fs = (float)ns_true;
    const float diff = rr / (fr * fr) - rs / (fr * fs);  // c_rr - c_rs
    atomicAdd(&accs[3], diff * diff);
    atomicAdd(&accs[4], 1.0f);
  }
}

// ---- Final combine: reduce orth partials, KL, MSEL; store f32/bf16 -------
__global__ __launch_bounds__(256) void InnovationLoss_88124138979690_kernel(
    const float* p_final, const int* counts, const float* accs, const float* orth_part,
    void* out, const int* flag) {
  __shared__ float lds4[4];
  const int t = threadIdx.x;
  const float nr = blockSum((float)counts[t], lds4);        // total rgb rows
  const float ns = blockSum((float)counts[L_ + t], lds4);   // total sar rows
  const float fr = fmaxf(nr, 1.f), fs = fmaxf(ns, 1.f);
  float klp = 0.f;
  for (int c = t; c < C_; c += 256) {
    const float pr = p_final[c] / fr;
    const float ps = p_final[C_ + c] / fs;
    klp += (ps - pr) * (logf(ps) - logf(pr));
  }
  klp = blockSum(klp, lds4);
  float o0 = 0.f, o1 = 0.f, o2 = 0.f;
  for (int b = t; b < ORTH_WAVES; b += 256) {
    o0 += orth_part[b];
    o1 += orth_part[ORTH_WAVES + b];
    o2 += orth_part[2 * ORTH_WAVES + b];
  }
  o0 = blockSum(o0, lds4);
  o1 = blockSum(o1, lds4);
  o2 = blockSum(o2, lds4);
  if (t == 0) {
    const float kl = (nr > 0.f && ns > 0.f) ? 0.5f * klp : 0.f;
    const float msel_cnt = accs[4];
    const float msel = msel_cnt > 0.f ? accs[3] / fmaxf(msel_cnt, 1.f) : 0.f;
    const float orth = (o0 + o1 + o2) * (1.0f / (float)B_);
    const float res = 0.5f * msel + 0.1f * orth + 0.1f * kl;
    if (*flag) ((bf16raw*)out)[0] = f2b(res);   // bf16 output (2 bytes)
    else       ((float*)out)[0]   = res;        // f32 output (4 bytes)
  }
}

extern "C" __attribute__((visibility("default")))
void kernel_launch(void* const* d_in, const int* in_sizes, int n_in,
                   void* d_out, int out_size, void* d_ws, size_t ws_size,
                   hipStream_t stream) {
  const void* feat   = d_in[0];
  const void* dee1   = d_in[1];
  const void* dee2   = d_in[2];
  const void* dee3   = d_in[3];
  const void* logits = d_in[4];
  const int*  labels = (const int*)d_in[5];
  const int*  modal  = (const int*)d_in[6];

  // workspace layout:
  //   counts    @ 0      : 512 i32      (2,048 B)
  //   accs      @ 2048   : 16 f32       (64 B)  [3]=msel_sum [4]=msel_cnt
  //   p_final   @ 2112   : 2000 f32     (8,000 B)
  //   rowlist   @ 10112  : 512*64 i32   (131,072 B)
  //   flag      @ 141184 : 1 i32
  //   norms     @ 141248 : 8192 f32     (32,768 B)
  //   orth_part @ 174016 : 3*1024 f32   (12,288 B)
  char* ws = (char*)d_ws;
  int*   counts    = (int*)  (ws);
  float* accs      = (float*)(ws + 2048);
  float* p_final   = (float*)(ws + 2112);
  int*   rowlist   = (int*)  (ws + 10112);
  int*   flag      = (int*)  (ws + 141184);
  float* norms     = (float*)(ws + 141248);
  float* orth_part = (float*)(ws + 174016);

  detect_kernel<<<1, 256, 0, stream>>>((const unsigned int*)feat, flag);
  init_kernel<<<8, 256, 0, stream>>>(counts, accs, p_final);
  bin_kernel<<<B_ / 256, 256, 0, stream>>>(labels, modal, counts, rowlist);
  fused_stream_kernel<<<FUSED_GRID, 256, 0, stream>>>(dee1, dee2, dee3, feat, logits,
                                                      modal, orth_part, norms, p_final,
                                                      flag);
  label_kernel<<<L_, 256, 0, stream>>>(feat, counts, rowlist, norms, accs, flag);
  InnovationLoss_88124138979690_kernel<<<1, 256, 0, stream>>>(p_final, counts, accs,
                                                              orth_part, d_out, flag);
}

// Round 4
// 306.757 us; speedup vs baseline: 1.2156x; 1.0137x over previous
//
#include <hip/hip_runtime.h>
#include <math.h>

#define B_   8192
#define D_   2048
#define C_   1000
#define L_   256
#define BIN_CAP 64

#define BIN_BLK  32    // 32 blk * 256 thr           -> 8192 rows binned
#define ORTH_BLK 512   // 512 blk * 4 waves * 4 rows -> 8192 rows
#define NORM_BLK 128   // 128 blk * 4 waves * 16 rows-> 8192 rows
#define CONS_BLK 128   // 128 blk * 4 waves * 16 rows-> 8192 rows
#define GRID_ (BIN_BLK + ORTH_BLK + NORM_BLK + CONS_BLK)
#define ORTH_WAVES (ORTH_BLK * 4)   // 2048 partial-sum slots

typedef unsigned short bf16raw;

__device__ __forceinline__ float bflo(unsigned int u) { return __uint_as_float(u << 16); }
__device__ __forceinline__ float bfhi(unsigned int u) { return __uint_as_float(u & 0xffff0000u); }

// round-to-nearest-even f32 -> bf16 bits (finite inputs)
__device__ __forceinline__ bf16raw f2b(float f) {
  unsigned int x = __float_as_uint(f);
  unsigned int r = (x + 0x7fffu + ((x >> 16) & 1u)) >> 16;
  return (bf16raw)r;
}

__device__ __forceinline__ void dec8(uint4 u, float* x) {
  x[0] = bflo(u.x); x[1] = bfhi(u.x);
  x[2] = bflo(u.y); x[3] = bfhi(u.y);
  x[4] = bflo(u.z); x[5] = bfhi(u.z);
  x[6] = bflo(u.w); x[7] = bfhi(u.w);
}

__device__ __forceinline__ float waveSum(float v) {
#pragma unroll
  for (int off = 32; off > 0; off >>= 1) v += __shfl_xor(v, off, 64);
  return v;
}

__device__ __forceinline__ float blockSum(float v, float* lds4) {
  v = waveSum(v);
  const int wave = threadIdx.x >> 6;
  if ((threadIdx.x & 63) == 0) lds4[wave] = v;
  __syncthreads();
  v = lds4[0] + lds4[1] + lds4[2] + lds4[3];
  __syncthreads();
  return v;
}

// per-block bf16-vs-f32 detect from feat's first 1 KB (L2 broadcast, ~free)
__device__ __forceinline__ int detect_isb(const unsigned int* feat_words, float* lds4) {
  const unsigned int w = feat_words[threadIdx.x];
  const float a = fabsf(bflo(w));
  float hit = (a > 1e-3f && a < 10.f) ? 1.f : 0.f;
  hit = blockSum(hit, lds4);
  return hit > 128.f ? 1 : 0;
}

// ---- init: zero scratch (counts, accs, p_final) --------------------------
__global__ __launch_bounds__(256) void init_kernel(int* counts, float* accs,
                                                   float* p_final) {
  const int t = blockIdx.x * 256 + threadIdx.x;
  if (t < 2 * L_) counts[t] = 0;
  if (t < 16) accs[t] = 0.f;
  if (t < 2 * C_) p_final[t] = 0.f;
}

__device__ __forceinline__ void ldrow3(const bf16raw* pa, const bf16raw* pb,
                                       const bf16raw* pc, size_t base, int lane,
                                       uint4 (&A)[4], uint4 (&Bv)[4], uint4 (&Cv)[4]) {
  const uint4* qa = (const uint4*)(pa + base);
  const uint4* qb = (const uint4*)(pb + base);
  const uint4* qc = (const uint4*)(pc + base);
#pragma unroll
  for (int j = 0; j < 4; ++j) A[j] = qa[j * 64 + lane];
#pragma unroll
  for (int j = 0; j < 4; ++j) Bv[j] = qb[j * 64 + lane];
#pragma unroll
  for (int j = 0; j < 4; ++j) Cv[j] = qc[j * 64 + lane];
}

__device__ __forceinline__ void orth_rowacc(const uint4 (&A)[4], const uint4 (&Bv)[4],
                                            const uint4 (&Cv)[4], float (&v)[6]) {
#pragma unroll
  for (int j = 0; j < 4; ++j) {
    float a[8], b[8], c[8];
    dec8(A[j], a); dec8(Bv[j], b); dec8(Cv[j], c);
#pragma unroll
    for (int k = 0; k < 8; ++k) {
      v[0] += a[k] * a[k]; v[1] += b[k] * b[k]; v[2] += c[k] * c[k];
      v[3] += a[k] * b[k]; v[4] += a[k] * c[k]; v[5] += b[k] * c[k];
    }
  }
}

__device__ __forceinline__ float ssq4(const uint4 (&X)[4]) {
  float ss = 0.f;
#pragma unroll
  for (int j = 0; j < 4; ++j) {
    float x[8]; dec8(X[j], x);
#pragma unroll
    for (int k = 0; k < 8; ++k) ss += x[k] * x[k];
  }
  return ss;
}

__device__ __forceinline__ void loadlogits_f32(const void* logits, int r, int lane,
                                               float (&x)[16]) {
#pragma unroll
  for (int kk = 0; kk < 4; ++kk) {
    const int idx = lane + (kk << 6);  // valid < 250
    if (idx < (C_ / 4)) {
      const float4 w = ((const float4*)((const float*)logits + (size_t)r * C_))[idx];
      x[4 * kk + 0] = w.x; x[4 * kk + 1] = w.y;
      x[4 * kk + 2] = w.z; x[4 * kk + 3] = w.w;
    } else {
      x[4 * kk + 0] = -INFINITY; x[4 * kk + 1] = -INFINITY;
      x[4 * kk + 2] = -INFINITY; x[4 * kk + 3] = -INFINITY;
    }
  }
}

__device__ __forceinline__ void softmax_acc(float (&x)[16], int m, float (&accA)[16],
                                            float (&accB)[16]) {
  float mx = -INFINITY;
#pragma unroll
  for (int k = 0; k < 16; ++k) mx = fmaxf(mx, x[k]);
#pragma unroll
  for (int off = 32; off > 0; off >>= 1) mx = fmaxf(mx, __shfl_xor(mx, off, 64));
  float s = 0.f;
#pragma unroll
  for (int k = 0; k < 16; ++k) { x[k] = expf(x[k] - mx); s += x[k]; }
#pragma unroll
  for (int off = 32; off > 0; off >>= 1) s += __shfl_xor(s, off, 64);
  const float inv = 1.f / s;
  if (m == 0) {
#pragma unroll
    for (int k = 0; k < 16; ++k) accA[k] += x[k] * inv;
  } else {
#pragma unroll
    for (int k = 0; k < 16; ++k) accB[k] += x[k] * inv;
  }
}

// ---- fused main: bin | orth | norms | cons in one dispatch ---------------
__global__ __launch_bounds__(256) void fused_main_kernel(
    const void* feat, const void* f1, const void* f2, const void* f3,
    const void* logits, const int* labels, const int* modal,
    int* counts, int* rowlist, float* orth_part, float* norms, float* p_final) {
  __shared__ float wacc[4][2][1024];  // cons blocks only (32 KB)
  __shared__ float lds4[4];
  const int t = threadIdx.x;
  const int wave = t >> 6, lane = t & 63;
  const int isb = detect_isb((const unsigned int*)feat, lds4);
  const int bx = blockIdx.x;

  if (bx < BIN_BLK) {
    // ---- bin rows by (modal, label); counts zeroed by init_kernel ----
    const int r = bx * 256 + t;
    const int m = modal[r] ? 1 : 0;
    int lb = labels[r]; lb = lb < 0 ? 0 : (lb >= L_ ? L_ - 1 : lb);
    const int key = m * L_ + lb;
    const int idx = atomicAdd(&counts[key], 1);
    if (idx < BIN_CAP) rowlist[key * BIN_CAP + idx] = r;
  } else if (bx < BIN_BLK + ORTH_BLK) {
    // ---- orthogonality: 1 wave = 4 full rows ----
    const int gw = (bx - BIN_BLK) * 4 + wave;  // 0..2047
    float s12 = 0.f, s13 = 0.f, s23 = 0.f;
    if (isb) {
      const bf16raw* pa = (const bf16raw*)f1;
      const bf16raw* pb = (const bf16raw*)f2;
      const bf16raw* pc = (const bf16raw*)f3;
      for (int r = 0; r < 4; ++r) {
        const size_t base = ((size_t)gw * 4 + r) * D_;
        uint4 A[4], Bv[4], Cv[4];
        ldrow3(pa, pb, pc, base, lane, A, Bv, Cv);
        float v[6] = {0.f, 0.f, 0.f, 0.f, 0.f, 0.f};
        orth_rowacc(A, Bv, Cv, v);
#pragma unroll
        for (int off = 32; off > 0; off >>= 1) {
#pragma unroll
          for (int j = 0; j < 6; ++j) v[j] += __shfl_xor(v[j], off, 64);
        }
        const float q1 = fmaxf(sqrtf(v[0]), 1e-12f);
        const float q2 = fmaxf(sqrtf(v[1]), 1e-12f);
        const float q3 = fmaxf(sqrtf(v[2]), 1e-12f);
        s12 += fabsf(v[3]) / (q1 * q2);
        s13 += fabsf(v[4]) / (q1 * q3);
        s23 += fabsf(v[5]) / (q2 * q3);
      }
    } else {
      for (int r = 0; r < 4; ++r) {
        const size_t base = ((size_t)gw * 4 + r) * D_;
        const float4* qa = (const float4*)((const float*)f1 + base);
        const float4* qb = (const float4*)((const float*)f2 + base);
        const float4* qc = (const float4*)((const float*)f3 + base);
        float v[6] = {0.f, 0.f, 0.f, 0.f, 0.f, 0.f};
#pragma unroll
        for (int h = 0; h < 8; ++h) {
          const float4 a4 = qa[h * 64 + lane];
          const float4 b4 = qb[h * 64 + lane];
          const float4 c4 = qc[h * 64 + lane];
          const float a[4] = {a4.x, a4.y, a4.z, a4.w};
          const float b[4] = {b4.x, b4.y, b4.z, b4.w};
          const float c[4] = {c4.x, c4.y, c4.z, c4.w};
#pragma unroll
          for (int k = 0; k < 4; ++k) {
            v[0] += a[k] * a[k]; v[1] += b[k] * b[k]; v[2] += c[k] * c[k];
            v[3] += a[k] * b[k]; v[4] += a[k] * c[k]; v[5] += b[k] * c[k];
          }
        }
#pragma unroll
        for (int off = 32; off > 0; off >>= 1) {
#pragma unroll
          for (int j = 0; j < 6; ++j) v[j] += __shfl_xor(v[j], off, 64);
        }
        const float q1 = fmaxf(sqrtf(v[0]), 1e-12f);
        const float q2 = fmaxf(sqrtf(v[1]), 1e-12f);
        const float q3 = fmaxf(sqrtf(v[2]), 1e-12f);
        s12 += fabsf(v[3]) / (q1 * q2);
        s13 += fabsf(v[4]) / (q1 * q3);
        s23 += fabsf(v[5]) / (q2 * q3);
      }
    }
    if (lane == 0) {
      orth_part[gw] = s12;
      orth_part[ORTH_WAVES + gw] = s13;
      orth_part[2 * ORTH_WAVES + gw] = s23;
    }
  } else if (bx < BIN_BLK + ORTH_BLK + NORM_BLK) {
    // ---- feat inverse row norms: 1 wave = 16 rows ----
    const int gw = (bx - BIN_BLK - ORTH_BLK) * 4 + wave;  // 0..511
    const size_t base0 = (size_t)gw * (16 * D_);
    if (isb) {
      const bf16raw* pf = (const bf16raw*)feat;
      for (int r = 0; r < 16; ++r) {
        const uint4* q = (const uint4*)(pf + base0 + (size_t)r * D_);
        uint4 X[4];
#pragma unroll
        for (int j = 0; j < 4; ++j) X[j] = q[j * 64 + lane];
        float ss = ssq4(X);
        ss = waveSum(ss);
        if (lane == 0) norms[gw * 16 + r] = 1.f / fmaxf(sqrtf(ss), 1e-12f);
      }
    } else {
      for (int r = 0; r < 16; ++r) {
        const float4* q = (const float4*)((const float*)feat + base0 + (size_t)r * D_);
        float ss = 0.f;
#pragma unroll
        for (int j = 0; j < 8; ++j) {
          const float4 w = q[j * 64 + lane];
          ss += w.x * w.x + w.y * w.y + w.z * w.z + w.w * w.w;
        }
        ss = waveSum(ss);
        if (lane == 0) norms[gw * 16 + r] = 1.f / fmaxf(sqrtf(ss), 1e-12f);
      }
    }
  } else {
    // ---- consistency: 1 wave = 16 rows, 1-ahead prefetch ----
    const int cb = bx - BIN_BLK - ORTH_BLK - NORM_BLK;  // 0..127
    const int rbase = cb * 64 + wave * 16;
    float accA[16], accB[16];
#pragma unroll
    for (int k = 0; k < 16; ++k) { accA[k] = 0.f; accB[k] = 0.f; }
    if (isb) {
      const bf16raw* pl = (const bf16raw*)logits;
      uint4 W0a, W1a;
      uint4 W0b = make_uint4(0u, 0u, 0u, 0u), W1b = make_uint4(0u, 0u, 0u, 0u);
      int ma, mb = 0;
      {
        const uint4* q = (const uint4*)(pl + (size_t)rbase * C_);
        W0a = q[lane];
        W1a = (lane < 61) ? q[64 + lane] : make_uint4(0u, 0u, 0u, 0u);
        ma = modal[rbase];
      }
      for (int i = 0; i < 16; ++i) {
        if (i < 15) {
          const int rn = rbase + i + 1;
          const uint4* q = (const uint4*)(pl + (size_t)rn * C_);
          W0b = q[lane];
          W1b = (lane < 61) ? q[64 + lane] : make_uint4(0u, 0u, 0u, 0u);
          mb = modal[rn];
        }
        float x[16];
        dec8(W0a, x);
        if (lane < 61) {
          float xx[8]; dec8(W1a, xx);
#pragma unroll
          for (int k = 0; k < 8; ++k) x[8 + k] = xx[k];
        } else {
#pragma unroll
          for (int k = 0; k < 8; ++k) x[8 + k] = -INFINITY;
        }
        softmax_acc(x, ma, accA, accB);
        W0a = W0b; W1a = W1b; ma = mb;
      }
#pragma unroll
      for (int k = 0; k < 16; ++k) {
        const int c = (k < 8) ? (8 * lane + k) : (512 + 8 * lane + (k - 8));
        wacc[wave][0][c] = accA[k];
        wacc[wave][1][c] = accB[k];
      }
    } else {
      float xa[16], xb[16];
      int ma, mb = 0;
      loadlogits_f32(logits, rbase, lane, xa);
      ma = modal[rbase];
      for (int i = 0; i < 16; ++i) {
        if (i < 15) {
          loadlogits_f32(logits, rbase + i + 1, lane, xb);
          mb = modal[rbase + i + 1];
        }
        softmax_acc(xa, ma, accA, accB);
#pragma unroll
        for (int k = 0; k < 16; ++k) xa[k] = xb[k];
        ma = mb;
      }
#pragma unroll
      for (int k = 0; k < 16; ++k) {
        const int c = 4 * (lane + ((k >> 2) << 6)) + (k & 3);
        wacc[wave][0][c] = accA[k];
        wacc[wave][1][c] = accB[k];
      }
    }
    __syncthreads();
    for (int e = t; e < 2 * C_; e += 256) {
      const int m = (e < C_) ? 0 : 1;
      const int c = e - m * C_;
      atomicAdd(&p_final[e],
                wacc[0][m][c] + wacc[1][m][c] + wacc[2][m][c] + wacc[3][m][c]);
    }
  }
}

// ---- MSEL fused center+label: one block per label, 2-ahead prefetch ------
__global__ __launch_bounds__(256) void label_kernel(const void* feat, const int* counts,
                                                    const int* rowlist, const float* norms,
                                                    float* accs) {
  __shared__ float lds4[4];
  const int l = blockIdx.x;
  const int t = threadIdx.x;
  const int isb = detect_isb((const unsigned int*)feat, lds4);
  const int nr_true = counts[l];
  const int ns_true = counts[L_ + l];
  const int nr = nr_true < BIN_CAP ? nr_true : BIN_CAP;
  const int ns = ns_true < BIN_CAP ? ns_true : BIN_CAP;
  const int tot = nr + ns;
  float accR[8], accS[8];
#pragma unroll
  for (int j = 0; j < 8; ++j) { accR[j] = 0.f; accS[j] = 0.f; }

  if (tot > 0) {
    auto rowAt = [&](int i) -> int {
      const int key = (i < nr) ? l : (L_ + l);
      const int idx = (i < nr) ? i : (i - nr);
      return rowlist[key * BIN_CAP + idx];
    };
    if (isb) {
      const bf16raw* pf = (const bf16raw*)feat;
      const int r0 = rowAt(0);
      uint4 qa = ((const uint4*)(pf + (size_t)r0 * D_))[t];
      float na = norms[r0];
      uint4 qb = make_uint4(0u, 0u, 0u, 0u);
      float nb2 = 0.f;
      if (tot > 1) {
        const int r1 = rowAt(1);
        qb = ((const uint4*)(pf + (size_t)r1 * D_))[t];
        nb2 = norms[r1];
      }
      for (int i = 0; i < tot; i += 2) {
        uint4 qc = make_uint4(0u, 0u, 0u, 0u), qd = make_uint4(0u, 0u, 0u, 0u);
        float nc = 0.f, nd = 0.f;
        if (i + 2 < tot) {
          const int rc = rowAt(i + 2);
          qc = ((const uint4*)(pf + (size_t)rc * D_))[t];
          nc = norms[rc];
        }
        if (i + 3 < tot) {
          const int rd = rowAt(i + 3);
          qd = ((const uint4*)(pf + (size_t)rd * D_))[t];
          nd = norms[rd];
        }
        {
          float x[8]; dec8(qa, x);
          if (i < nr) {
#pragma unroll
            for (int j = 0; j < 8; ++j) accR[j] += x[j] * na;
          } else {
#pragma unroll
            for (int j = 0; j < 8; ++j) accS[j] += x[j] * na;
          }
        }
        if (i + 1 < tot) {
          float x[8]; dec8(qb, x);
          if (i + 1 < nr) {
#pragma unroll
            for (int j = 0; j < 8; ++j) accR[j] += x[j] * nb2;
          } else {
#pragma unroll
            for (int j = 0; j < 8; ++j) accS[j] += x[j] * nb2;
          }
        }
        qa = qc; qb = qd; na = nc; nb2 = nd;
      }
    } else {
      const float* pf = (const float*)feat;
      const int r0 = rowAt(0);
      float4 a0 = ((const float4*)(pf + (size_t)r0 * D_))[2 * t];
      float4 a1 = ((const float4*)(pf + (size_t)r0 * D_))[2 * t + 1];
      float na = norms[r0];
      float4 b0 = make_float4(0.f, 0.f, 0.f, 0.f), b1 = make_float4(0.f, 0.f, 0.f, 0.f);
      float nb2 = 0.f;
      if (tot > 1) {
        const int r1 = rowAt(1);
        b0 = ((const float4*)(pf + (size_t)r1 * D_))[2 * t];
        b1 = ((const float4*)(pf + (size_t)r1 * D_))[2 * t + 1];
        nb2 = norms[r1];
      }
      for (int i = 0; i < tot; i += 2) {
        float4 c0 = make_float4(0.f, 0.f, 0.f, 0.f), c1 = c0, d0 = c0, d1 = c0;
        float nc = 0.f, nd = 0.f;
        if (i + 2 < tot) {
          const int rc = rowAt(i + 2);
          c0 = ((const float4*)(pf + (size_t)rc * D_))[2 * t];
          c1 = ((const float4*)(pf + (size_t)rc * D_))[2 * t + 1];
          nc = norms[rc];
        }
        if (i + 3 < tot) {
          const int rd = rowAt(i + 3);
          d0 = ((const float4*)(pf + (size_t)rd * D_))[2 * t];
          d1 = ((const float4*)(pf + (size_t)rd * D_))[2 * t + 1];
          nd = norms[rd];
        }
        {
          const float x[8] = {a0.x, a0.y, a0.z, a0.w, a1.x, a1.y, a1.z, a1.w};
          if (i < nr) {
#pragma unroll
            for (int j = 0; j < 8; ++j) accR[j] += x[j] * na;
          } else {
#pragma unroll
            for (int j = 0; j < 8; ++j) accS[j] += x[j] * na;
          }
        }
        if (i + 1 < tot) {
          const float x[8] = {b0.x, b0.y, b0.z, b0.w, b1.x, b1.y, b1.z, b1.w};
          if (i + 1 < nr) {
#pragma unroll
            for (int j = 0; j < 8; ++j) accR[j] += x[j] * nb2;
          } else {
#pragma unroll
            for (int j = 0; j < 8; ++j) accS[j] += x[j] * nb2;
          }
        }
        a0 = c0; a1 = c1; b0 = d0; b1 = d1; na = nc; nb2 = nd;
      }
    }
  }
  float rr = 0.f, rs = 0.f;
#pragma unroll
  for (int j = 0; j < 8; ++j) { rr += accR[j] * accR[j]; rs += accR[j] * accS[j]; }
  rr = blockSum(rr, lds4);
  rs = blockSum(rs, lds4);
  if (t == 0 && nr_true >= 2 && ns_true >= 1) {
    const float fr = (float)nr_true, fs = (float)ns_true;
    const float diff = rr / (fr * fr) - rs / (fr * fs);  // c_rr - c_rs
    atomicAdd(&accs[3], diff * diff);
    atomicAdd(&accs[4], 1.0f);
  }
}

// ---- Final combine: reduce orth partials, KL, MSEL; store f32/bf16 -------
__global__ __launch_bounds__(256) void InnovationLoss_88124138979690_kernel(
    const void* feat, const float* p_final, const int* counts, const float* accs,
    const float* orth_part, void* out) {
  __shared__ float lds4[4];
  const int t = threadIdx.x;
  const int isb = detect_isb((const unsigned int*)feat, lds4);
  const float nr = blockSum((float)counts[t], lds4);        // total rgb rows
  const float ns = blockSum((float)counts[L_ + t], lds4);   // total sar rows
  const float fr = fmaxf(nr, 1.f), fs = fmaxf(ns, 1.f);
  float klp = 0.f;
  for (int c = t; c < C_; c += 256) {
    const float pr = p_final[c] / fr;
    const float ps = p_final[C_ + c] / fs;
    klp += (ps - pr) * (logf(ps) - logf(pr));
  }
  klp = blockSum(klp, lds4);
  float o0 = 0.f, o1 = 0.f, o2 = 0.f;
  for (int b = t; b < ORTH_WAVES; b += 256) {
    o0 += orth_part[b];
    o1 += orth_part[ORTH_WAVES + b];
    o2 += orth_part[2 * ORTH_WAVES + b];
  }
  o0 = blockSum(o0, lds4);
  o1 = blockSum(o1, lds4);
  o2 = blockSum(o2, lds4);
  if (t == 0) {
    const float kl = (nr > 0.f && ns > 0.f) ? 0.5f * klp : 0.f;
    const float msel_cnt = accs[4];
    const float msel = msel_cnt > 0.f ? accs[3] / fmaxf(msel_cnt, 1.f) : 0.f;
    const float orth = (o0 + o1 + o2) * (1.0f / (float)B_);
    const float res = 0.5f * msel + 0.1f * orth + 0.1f * kl;
    if (isb) ((bf16raw*)out)[0] = f2b(res);   // bf16 output (2 bytes)
    else     ((float*)out)[0]   = res;        // f32 output (4 bytes)
  }
}

extern "C" __attribute__((visibility("default")))
void kernel_launch(void* const* d_in, const int* in_sizes, int n_in,
                   void* d_out, int out_size, void* d_ws, size_t ws_size,
                   hipStream_t stream) {
  const void* feat   = d_in[0];
  const void* dee1   = d_in[1];
  const void* dee2   = d_in[2];
  const void* dee3   = d_in[3];
  const void* logits = d_in[4];
  const int*  labels = (const int*)d_in[5];
  const int*  modal  = (const int*)d_in[6];

  // workspace layout (198,528 bytes total):
  //   counts    @ 0      : 512 i32      (2,048 B)  -+
  //   accs      @ 2048   : 16 f32       (64 B)      |-- zeroed by init_kernel
  //   p_final   @ 2112   : 2000 f32     (8,000 B)  -+
  //   rowlist   @ 10112  : 512*64 i32   (131,072 B)
  //   norms     @ 141184 : 8192 f32     (32,768 B)
  //   orth_part @ 173952 : 3*2048 f32   (24,576 B)
  char* ws = (char*)d_ws;
  int*   counts    = (int*)  (ws);
  float* accs      = (float*)(ws + 2048);
  float* p_final   = (float*)(ws + 2112);
  int*   rowlist   = (int*)  (ws + 10112);
  float* norms     = (float*)(ws + 141184);
  float* orth_part = (float*)(ws + 173952);

  init_kernel<<<8, 256, 0, stream>>>(counts, accs, p_final);
  fused_main_kernel<<<GRID_, 256, 0, stream>>>(feat, dee1, dee2, dee3, logits, labels,
                                               modal, counts, rowlist, orth_part, norms,
                                               p_final);
  label_kernel<<<L_, 256, 0, stream>>>(feat, counts, rowlist, norms, accs);
  InnovationLoss_88124138979690_kernel<<<1, 256, 0, stream>>>(feat, p_final, counts,
                                                              accs, orth_part, d_out);
}